// Round 1
// baseline (335.058 us; speedup 1.0000x reference)
//
#include <hip/hip_runtime.h>

// 2-layer LSTM (H=64) encode(128) + AR(60) for B=4096, persistent per-block.
// grid=256 blocks x 256 threads; block owns M=16 batch elements for all 188 steps.
// Weights held in registers as fp16 MFMA B-fragments; h state round-trips LDS.

#define T_ENC 128
#define D_IN 4
#define H 64
#define STEPS 60
#define M 16
#define A0_STRIDE 104   // halves per row: K0pad(96) + 8 pad (keeps 16B align, breaks bank stride)
#define A1_STRIDE 136   // 128 + 8

typedef _Float16 half8 __attribute__((ext_vector_type(8)));
typedef float float4v __attribute__((ext_vector_type(4)));

__device__ __forceinline__ float fast_sigmoid(float x) {
    float e = __builtin_amdgcn_exp2f(-1.44269504f * x);
    return __builtin_amdgcn_rcpf(1.0f + e);
}
__device__ __forceinline__ float fast_tanh(float x) {
    // tanh(x) = 1 - 2/(exp(2x)+1); robust at +/-inf of exp2
    float e = __builtin_amdgcn_exp2f(2.88539008f * x);
    return __builtin_fmaf(-2.0f, __builtin_amdgcn_rcpf(e + 1.0f), 1.0f);
}

__global__ __launch_bounds__(256, 1) void lstm_ar_kernel(
    const float* __restrict__ x,
    const float* __restrict__ Wih0, const float* __restrict__ Whh0,
    const float* __restrict__ bih0, const float* __restrict__ bhh0,
    const float* __restrict__ Wih1, const float* __restrict__ Whh1,
    const float* __restrict__ bih1, const float* __restrict__ bhh1,
    const float* __restrict__ Wfc,  const float* __restrict__ bfc,
    float* __restrict__ out)
{
    __shared__ __align__(16) _Float16 A0buf[M * A0_STRIDE];  // [x(4); h0(64); zero-pad]
    __shared__ __align__(16) _Float16 A1buf[M * A1_STRIDE];  // [h0_new(64); h1_prev(64)]
    __shared__ float WfcS[D_IN * H];
    __shared__ float bfcS[D_IN];

    const int tid  = threadIdx.x;
    const int wave = tid >> 6;
    const int lane = tid & 63;
    const int n16  = lane & 15;
    const int quad = lane >> 4;
    const int m0   = blockIdx.x * M;

    // ---- init LDS ----
    for (int i = tid; i < M * A0_STRIDE; i += 256) A0buf[i] = (_Float16)0.f;
    for (int i = tid; i < M * A1_STRIDE; i += 256) A1buf[i] = (_Float16)0.f;
    WfcS[tid & 255] = Wfc[tid & 255];       // 256 floats, blockDim==256
    if (tid < D_IN) bfcS[tid] = bfc[tid];

    // ---- weight B-fragments into registers (fp16) ----
    // B[k][n] fragment layout: n = 16*(wave+4*tau) + (lane&15), k = kt*32 + quad*8 + j
    half8 B0f[3][4];
    half8 B1f[4][4];
    float b0v[4], b1v[4];
    #pragma unroll
    for (int tau = 0; tau < 4; ++tau) {
        const int n = 16 * (wave + 4 * tau) + n16;   // gate row index in [0,256)
        b0v[tau] = bih0[n] + bhh0[n];
        b1v[tau] = bih1[n] + bhh1[n];
        #pragma unroll
        for (int kt = 0; kt < 3; ++kt) {
            #pragma unroll
            for (int j = 0; j < 8; ++j) {
                const int k = kt * 32 + quad * 8 + j;
                float v = 0.f;
                if (k < 4)       v = Wih0[n * D_IN + k];
                else if (k < 68) v = Whh0[n * H + (k - 4)];
                B0f[kt][tau][j] = (_Float16)v;
            }
        }
        #pragma unroll
        for (int kt = 0; kt < 4; ++kt) {
            #pragma unroll
            for (int j = 0; j < 8; ++j) {
                const int k = kt * 32 + quad * 8 + j;
                const float v = (k < H) ? Wih1[n * H + k] : Whh1[n * H + (k - H)];
                B1f[kt][tau][j] = (_Float16)v;
            }
        }
    }

    float c0s[4] = {0.f, 0.f, 0.f, 0.f};
    float c1s[4] = {0.f, 0.f, 0.f, 0.f};

    __syncthreads();                 // zeroing done
    if (wave == 1) {                 // load x_0
        const int me = lane >> 2, d = lane & 3;
        A0buf[me * A0_STRIDE + d] =
            (_Float16)x[(size_t)(m0 + me) * T_ENC * D_IN + d];
    }
    __syncthreads();                 // x_0 visible

    const int m    = n16;            // A-fragment row (element) for this lane
    const int jcol = 16 * wave + n16;// hidden column this lane owns in epilogues

    for (int iter = 0; iter < T_ENC + STEPS; ++iter) {
        // ---- GEMM0: gates0 = [x; h0] @ W0^T ----
        float4v C0[4] = {};
        half8 a0[3];
        #pragma unroll
        for (int kt = 0; kt < 3; ++kt)
            a0[kt] = *(const half8*)&A0buf[m * A0_STRIDE + kt * 32 + quad * 8];
        #pragma unroll
        for (int kt = 0; kt < 3; ++kt)
            #pragma unroll
            for (int tau = 0; tau < 4; ++tau)
                C0[tau] = __builtin_amdgcn_mfma_f32_16x16x32_f16(
                    a0[kt], B0f[kt][tau], C0[tau], 0, 0, 0);
        __syncthreads();  // b1: A0 reads done -> A0buf writable

        // x prefetch for next iter (encode phase; iter==127 re-fetches x_127 for AR step 0)
        if (iter < T_ENC && wave == 1) {
            const int me = lane >> 2, d = lane & 3;
            const int t = (iter + 1 < T_ENC) ? iter + 1 : T_ENC - 1;
            A0buf[me * A0_STRIDE + d] =
                (_Float16)x[(size_t)(m0 + me) * T_ENC * D_IN + t * D_IN + d];
        }

        // ---- epilogue 0: cell update layer 0 (lane-local, c0 in regs) ----
        #pragma unroll
        for (int r = 0; r < 4; ++r) {
            const float ig = fast_sigmoid(C0[0][r] + b0v[0]);
            const float fg = fast_sigmoid(C0[1][r] + b0v[1]);
            const float gg = fast_tanh   (C0[2][r] + b0v[2]);
            const float og = fast_sigmoid(C0[3][r] + b0v[3]);
            const float c  = fg * c0s[r] + ig * gg;
            c0s[r] = c;
            const float h = og * fast_tanh(c);
            const _Float16 hh = (_Float16)h;
            const int row = quad * 4 + r;
            A1buf[row * A1_STRIDE + jcol] = hh;          // layer1 input (k = jcol)
            A0buf[row * A0_STRIDE + 4 + jcol] = hh;      // next step layer0 input
        }
        __syncthreads();  // b2: h0 visible

        // ---- GEMM1: gates1 = [h0_new; h1_prev] @ W1^T ----
        float4v C1[4] = {};
        half8 a1[4];
        #pragma unroll
        for (int kt = 0; kt < 4; ++kt)
            a1[kt] = *(const half8*)&A1buf[m * A1_STRIDE + kt * 32 + quad * 8];
        #pragma unroll
        for (int kt = 0; kt < 4; ++kt)
            #pragma unroll
            for (int tau = 0; tau < 4; ++tau)
                C1[tau] = __builtin_amdgcn_mfma_f32_16x16x32_f16(
                    a1[kt], B1f[kt][tau], C1[tau], 0, 0, 0);
        __syncthreads();  // b3: A1 reads done -> h1 writable

        // ---- epilogue 1: cell update layer 1 ----
        #pragma unroll
        for (int r = 0; r < 4; ++r) {
            const float ig = fast_sigmoid(C1[0][r] + b1v[0]);
            const float fg = fast_sigmoid(C1[1][r] + b1v[1]);
            const float gg = fast_tanh   (C1[2][r] + b1v[2]);
            const float og = fast_sigmoid(C1[3][r] + b1v[3]);
            const float c  = fg * c1s[r] + ig * gg;
            c1s[r] = c;
            const float h = og * fast_tanh(c);
            const int row = quad * 4 + r;
            A1buf[row * A1_STRIDE + H + jcol] = (_Float16)h;
        }

        if (iter >= T_ENC) {
            __syncthreads();  // b4: h1 visible for the head
            if (wave == 0) {
                const int me = lane >> 2, d = lane & 3;
                float acc = bfcS[d];
                #pragma unroll
                for (int kk = 0; kk < 8; ++kk) {
                    const half8 hv = *(const half8*)&A1buf[me * A1_STRIDE + H + kk * 8];
                    #pragma unroll
                    for (int j = 0; j < 8; ++j)
                        acc += (float)hv[j] * WfcS[d * H + kk * 8 + j];
                }
                const int s = iter - T_ENC;
                out[((size_t)(m0 + me) * STEPS + s) * D_IN + d] = acc;
                A0buf[me * A0_STRIDE + d] = (_Float16)acc;   // pred becomes next input
            }
            __syncthreads();  // b5: pred input visible
        }
    }
}

extern "C" void kernel_launch(void* const* d_in, const int* in_sizes, int n_in,
                              void* d_out, int out_size, void* d_ws, size_t ws_size,
                              hipStream_t stream) {
    const float* x    = (const float*)d_in[0];
    const float* Wih0 = (const float*)d_in[1];
    const float* Whh0 = (const float*)d_in[2];
    const float* bih0 = (const float*)d_in[3];
    const float* bhh0 = (const float*)d_in[4];
    const float* Wih1 = (const float*)d_in[5];
    const float* Whh1 = (const float*)d_in[6];
    const float* bih1 = (const float*)d_in[7];
    const float* bhh1 = (const float*)d_in[8];
    const float* Wfc  = (const float*)d_in[9];
    const float* bfc  = (const float*)d_in[10];
    float* out = (float*)d_out;

    dim3 grid(4096 / M);   // 256 blocks, one per CU
    dim3 block(256);
    lstm_ar_kernel<<<grid, block, 0, stream>>>(
        x, Wih0, Whh0, bih0, bhh0, Wih1, Whh1, bih1, bhh1, Wfc, bfc, out);
}